// Round 3
// baseline (48628.220 us; speedup 1.0000x reference)
//
#include <hip/hip_runtime.h>

// HMM forward: alpha_t = (alpha_{t-1} @ A) * B[:, obs_t], out = sum(alpha_{T-1})
// S=2048, V=32768, T=4096. Persistent cooperative kernel.
//
// R2: A lives in LDS (deterministic residency — R0/R1 proved the register
// allocator spills/rematerializes a 64-float per-thread array regardless of
// VGPR budget; R1's scratch spill cost +50%). 512 blocks x 256 threads,
// 4 columns per block, one wave per column. Per step: poll alpha via
// {tag,value} atomic pairs, stage to LDS, one barrier, 16x ds_read_b128 +
// 32 FMA per lane, 6x shfl_xor reduce, lane0 publishes.

#define S 2048
#define V 32768
#define T 4096
#define G 512          // blocks (2/CU), cooperative => co-resident
#define BT 256         // 4 waves
#define COLS 4         // columns of A per block
#define EPT 8          // poll entries per thread (2048/256)
#define RING 16        // b-value ring slots
#define DIST 8         // b prefetch distance (steps)

__global__ __launch_bounds__(BT, 2) void hmm_fwd(
    const int* __restrict__ obs,
    const float* __restrict__ A,
    const float* __restrict__ B,
    const float* __restrict__ pi,
    float* __restrict__ out,
    unsigned long long* __restrict__ buf)   // 2 * S pairs of {tag32, f32}
{
    const int g    = blockIdx.x;
    const int tid  = threadIdx.x;
    const int lane = tid & 63;
    const int wave = tid >> 6;            // 0..3 == column-within-block
    const int j    = g * COLS + wave;     // this wave's global column

    __shared__ float As[COLS * S];        // 32 KB: As[c*S + r] = A[r][g*4+c]
    __shared__ float alpha[S];            // 8 KB staged alpha_{t-1}
    __shared__ float bring[RING * COLS];  // prefetched B[j, obs_t]
    __shared__ float partial[4];          // final-reduce scratch (block 0)

    // ---- one-time: stage A slice into LDS, transposed to column-major.
    // Read pattern: 4 consecutive lanes cover the 4 columns of one row
    // (16B of a 64B line); rows stride by 64 per iteration. Coalesced.
    {
        const int c  = tid & 3;
        const int r0 = tid >> 2;
        const float* Ap = A + g * COLS + c;
#pragma unroll 4
        for (int it = 0; it < 32; ++it) {
            int r = r0 + 64 * it;
            As[c * S + r] = Ap[r * S];
        }
    }

    // ---- lane 0 of each wave: init b-ring (t=1..DIST) and publish alpha_0
    if (lane == 0) {
        for (int u = 1; u <= DIST; ++u) {
            int o = obs[u];
            bring[(u & (RING - 1)) * COLS + wave] = B[j * V + o];
        }
        int o0 = obs[0];
        float v = pi[j] * B[j * V + o0];
        unsigned long long p = (1ull << 32) | (unsigned long long)__float_as_uint(v);
        __hip_atomic_store(&buf[j], p, __ATOMIC_RELAXED, __HIP_MEMORY_SCOPE_AGENT);
    }

    for (int t = 1; t < T; ++t) {
        // ---- poll + stage alpha_{t-1} (tag == t); 8 entries (one 64B line)
        unsigned long long want = (unsigned long long)t;
        unsigned long long* src = buf + (((t - 1) & 1) * S) + EPT * tid;
        unsigned long long v[EPT];
        for (;;) {
            bool ok = true;
#pragma unroll
            for (int e = 0; e < EPT; ++e) {
                v[e] = __hip_atomic_load(&src[e], __ATOMIC_RELAXED,
                                         __HIP_MEMORY_SCOPE_AGENT);
                ok &= ((v[e] >> 32) == want);
            }
            if (ok) break;
            __builtin_amdgcn_s_sleep(1);
        }
        float4* adst = (float4*)(alpha + EPT * tid);
        float4 f0, f1;
        f0.x = __uint_as_float((unsigned)v[0]);
        f0.y = __uint_as_float((unsigned)v[1]);
        f0.z = __uint_as_float((unsigned)v[2]);
        f0.w = __uint_as_float((unsigned)v[3]);
        f1.x = __uint_as_float((unsigned)v[4]);
        f1.y = __uint_as_float((unsigned)v[5]);
        f1.z = __uint_as_float((unsigned)v[6]);
        f1.w = __uint_as_float((unsigned)v[7]);
        adst[0] = f0;
        adst[1] = f1;
        __syncthreads();   // the ONLY per-step barrier (also orders As init)

        // ---- prefetch b_{t+DIST} for this wave's column (overlaps dot)
        if (lane == 0) {
            int tp = t + DIST;
            if (tp < T) {
                int o = obs[tp];
                bring[(tp & (RING - 1)) * COLS + wave] = B[j * V + o];
            }
        }

        // ---- dot: full alpha (2048) against column j, 32 rows per lane
        float acc = 0.f;
        const float4* Ac = (const float4*)(As + wave * S);
        const float4* Al = (const float4*)alpha;
#pragma unroll
        for (int k = 0; k < 8; ++k) {
            float4 al = Al[k * 64 + lane];
            float4 av = Ac[k * 64 + lane];
            acc = fmaf(al.x, av.x, acc);
            acc = fmaf(al.y, av.y, acc);
            acc = fmaf(al.z, av.z, acc);
            acc = fmaf(al.w, av.w, acc);
        }
        // reduce across the 64 lanes
        acc += __shfl_xor(acc, 32, 64);
        acc += __shfl_xor(acc, 16, 64);
        acc += __shfl_xor(acc, 8, 64);
        acc += __shfl_xor(acc, 4, 64);
        acc += __shfl_xor(acc, 2, 64);
        acc += __shfl_xor(acc, 1, 64);

        // ---- publish: apply b_t, store {tag=t+1, value}
        if (lane == 0) {
            float val = acc * bring[(t & (RING - 1)) * COLS + wave];
            unsigned long long p = (((unsigned long long)(t + 1)) << 32) |
                                   (unsigned long long)__float_as_uint(val);
            __hip_atomic_store(&buf[(t & 1) * S + j], p,
                               __ATOMIC_RELAXED, __HIP_MEMORY_SCOPE_AGENT);
        }
    }

    // ---- final: block 0 sums alpha_{T-1} (tag == T) into out[0]
    if (g == 0) {
        unsigned long long want = (unsigned long long)T;
        unsigned long long* src = buf + (((T - 1) & 1) * S) + EPT * tid;
        float sm = 0.f;
        unsigned long long v[EPT];
        for (;;) {
            bool ok = true;
#pragma unroll
            for (int e = 0; e < EPT; ++e) {
                v[e] = __hip_atomic_load(&src[e], __ATOMIC_RELAXED,
                                         __HIP_MEMORY_SCOPE_AGENT);
                ok &= ((v[e] >> 32) == want);
            }
            if (ok) break;
            __builtin_amdgcn_s_sleep(1);
        }
#pragma unroll
        for (int e = 0; e < EPT; ++e) sm += __uint_as_float((unsigned)v[e]);
        sm += __shfl_down(sm, 32, 64);
        sm += __shfl_down(sm, 16, 64);
        sm += __shfl_down(sm, 8, 64);
        sm += __shfl_down(sm, 4, 64);
        sm += __shfl_down(sm, 2, 64);
        sm += __shfl_down(sm, 1, 64);
        if (lane == 0) partial[wave] = sm;
        __syncthreads();
        if (tid == 0) {
            float tot = partial[0] + partial[1] + partial[2] + partial[3];
            out[0] = tot;
        }
    }
}

extern "C" void kernel_launch(void* const* d_in, const int* in_sizes, int n_in,
                              void* d_out, int out_size, void* d_ws, size_t ws_size,
                              hipStream_t stream) {
    const int*   obs = (const int*)d_in[0];
    const float* A   = (const float*)d_in[1];
    const float* B   = (const float*)d_in[2];
    const float* pi  = (const float*)d_in[3];
    float* out = (float*)d_out;
    unsigned long long* buf = (unsigned long long*)d_ws;  // 2*S*8 = 32 KB

    // No memset needed: 0xAA poison tag 0xAAAAAAAA never matches tags [1,4096].

    void* args[] = { (void*)&obs, (void*)&A, (void*)&B, (void*)&pi,
                     (void*)&out, (void*)&buf };
    hipLaunchCooperativeKernel((void*)hmm_fwd, dim3(G), dim3(BT), args, 0, stream);
}

// Round 4
// 26381.876 us; speedup vs baseline: 1.8432x; 1.8432x over previous
//
#include <hip/hip_runtime.h>

// HMM forward: alpha_t = (alpha_{t-1} @ A) * B[:, obs_t], out = sum(alpha_{T-1})
// S=2048, V=32768, T=4096. Persistent cooperative kernel.
//
// R3 = R0's comm structure (128 blocks x 512 threads -- proven lowest poll
// contention) + A staged once in 128KB dynamic LDS (kills R0's dominant cost:
// per-step stride-8KB A re-reads from L2, ~64 lines per vmem instr).
//  - A layout: slot(c,k,q) = c*512 + k*64 + q float4s, holding rows
//    32q+4k..+3 of column c -> consecutive lanes read consecutive slots
//    (conflict-free ds_read_b128).
//  - LDS alpha DOUBLE-buffered: fixes a latent R1/R2 race (fast thread
//    restages alpha while a slow sibling wave still reads the old one).
//  - Publish per-wave AFTER the block barrier: barrier guard = full-block
//    poll of ALL entries => tag t+1 overwrites are safe device-wide.

#define S 2048
#define V 32768
#define T 4096
#define G 128          // blocks, cooperative => co-resident (1 per CU w/ big LDS)
#define BT 512         // 8 waves
#define COLS 16        // columns of A per block (2 per wave)
#define RING 16        // b-value ring slots
#define DIST 8         // b prefetch distance (steps)

// LDS floats: As 32768 | alpha 2x2176 | bring 256 | partial 8
#define SM_AS     0
#define SM_AB0    32768
#define SM_AB1    (32768 + 2176)
#define SM_BRING  (32768 + 2 * 2176)
#define SM_PART   (SM_BRING + RING * COLS)
#define SMEM_FLOATS (SM_PART + 8)
#define SMEM_BYTES  (SMEM_FLOATS * 4)   // 149,536 B

__global__ __launch_bounds__(BT, 1) void hmm_fwd(
    const int* __restrict__ obs,
    const float* __restrict__ A,
    const float* __restrict__ B,
    const float* __restrict__ pi,
    float* __restrict__ out,
    unsigned long long* __restrict__ buf)   // 2 * S pairs of {tag32, f32}
{
    extern __shared__ float smem[];
    float* As      = smem + SM_AS;
    float* bring   = smem + SM_BRING;
    float* partial = smem + SM_PART;

    const int g    = blockIdx.x;
    const int tid  = threadIdx.x;
    const int lane = tid & 63;
    const int wave = tid >> 6;
    const int c0   = 2 * wave;            // this wave's two columns
    const int c1   = 2 * wave + 1;
    const int j0   = g * COLS + c0;

    // ---- one-time: stage A slice into LDS (interleaved layout).
    // Thread reads float4 of 4 consecutive columns of one row (coalesced),
    // scatters 4 scalar floats into the per-column interleaved layout.
    {
        const int u  = tid & 3;           // column quad: cols 4u..4u+3
        const int r0 = tid >> 2;          // 128 rows per sweep
        for (int it = 0; it < 16; ++it) {
            int r = r0 + 128 * it;
            float4 av = *(const float4*)(A + (size_t)r * S + g * COLS + 4 * u);
            int q = r >> 5, k = (r & 31) >> 2, m = r & 3;
            int base = (k * 64 + q) * 4 + m;   // float offset within column
            As[(4 * u + 0) * 2048 + base] = av.x;
            As[(4 * u + 1) * 2048 + base] = av.y;
            As[(4 * u + 2) * 2048 + base] = av.z;
            As[(4 * u + 3) * 2048 + base] = av.w;
        }
    }

    // ---- lanes 0/32 of each wave: init b-ring (t=1..DIST), publish alpha_0
    if ((lane & 31) == 0) {
        int c = 2 * wave + (lane >> 5);
        int j = g * COLS + c;
        for (int u = 1; u <= DIST; ++u) {
            int o = obs[u];
            bring[(u & (RING - 1)) * COLS + c] = B[(size_t)j * V + o];
        }
        int o0 = obs[0];
        float v = pi[j] * B[(size_t)j * V + o0];
        unsigned long long p = (1ull << 32) | (unsigned long long)__float_as_uint(v);
        __hip_atomic_store(&buf[j], p, __ATOMIC_RELAXED, __HIP_MEMORY_SCOPE_AGENT);
    }

    for (int t = 1; t < T; ++t) {
        // ---- poll + stage alpha_{t-1} (tag == t); 4 entries per thread
        unsigned long long want = (unsigned long long)t;
        unsigned long long* src = buf + (((t - 1) & 1) * S) + 4 * tid;
        unsigned long long v0, v1, v2, v3;
        for (;;) {
            v0 = __hip_atomic_load(&src[0], __ATOMIC_RELAXED, __HIP_MEMORY_SCOPE_AGENT);
            v1 = __hip_atomic_load(&src[1], __ATOMIC_RELAXED, __HIP_MEMORY_SCOPE_AGENT);
            v2 = __hip_atomic_load(&src[2], __ATOMIC_RELAXED, __HIP_MEMORY_SCOPE_AGENT);
            v3 = __hip_atomic_load(&src[3], __ATOMIC_RELAXED, __HIP_MEMORY_SCOPE_AGENT);
            if ((v0 >> 32) == want && (v1 >> 32) == want &&
                (v2 >> 32) == want && (v3 >> 32) == want) break;
            __builtin_amdgcn_s_sleep(1);
        }
        float* ab = smem + (((t - 1) & 1) ? SM_AB1 : SM_AB0);  // double buffer
        float4 f;
        f.x = __uint_as_float((unsigned)v0);
        f.y = __uint_as_float((unsigned)v1);
        f.z = __uint_as_float((unsigned)v2);
        f.w = __uint_as_float((unsigned)v3);
        ((float4*)ab)[tid + (tid >> 4)] = f;      // padded: 2-way max (free)
        __syncthreads();   // the ONLY per-step barrier

        // ---- prefetch b_{t+DIST} for this wave's columns (overlaps dot)
        if ((lane & 31) == 0) {
            int tp = t + DIST;
            if (tp < T) {
                int c = 2 * wave + (lane >> 5);
                int o = obs[tp];
                bring[(tp & (RING - 1)) * COLS + c] = B[(size_t)(g * COLS + c) * V + o];
            }
        }

        // ---- dot: rows 32*lane..32*lane+31 of both columns (alpha read once)
        float acc0 = 0.f, acc1 = 0.f;
        const float4* Af = (const float4*)As;
        const float4* Av = (const float4*)ab;
#pragma unroll
        for (int k = 0; k < 8; ++k) {
            int p = 8 * lane + k;
            float4 al = Av[p + (p >> 4)];
            float4 a0 = Af[c0 * 512 + k * 64 + lane];
            float4 a1 = Af[c1 * 512 + k * 64 + lane];
            acc0 = fmaf(al.x, a0.x, acc0); acc1 = fmaf(al.x, a1.x, acc1);
            acc0 = fmaf(al.y, a0.y, acc0); acc1 = fmaf(al.y, a1.y, acc1);
            acc0 = fmaf(al.z, a0.z, acc0); acc1 = fmaf(al.z, a1.z, acc1);
            acc0 = fmaf(al.w, a0.w, acc0); acc1 = fmaf(al.w, a1.w, acc1);
        }
        // reduce across 64 lanes
        acc0 += __shfl_xor(acc0, 32, 64); acc1 += __shfl_xor(acc1, 32, 64);
        acc0 += __shfl_xor(acc0, 16, 64); acc1 += __shfl_xor(acc1, 16, 64);
        acc0 += __shfl_xor(acc0,  8, 64); acc1 += __shfl_xor(acc1,  8, 64);
        acc0 += __shfl_xor(acc0,  4, 64); acc1 += __shfl_xor(acc1,  4, 64);
        acc0 += __shfl_xor(acc0,  2, 64); acc1 += __shfl_xor(acc1,  2, 64);
        acc0 += __shfl_xor(acc0,  1, 64); acc1 += __shfl_xor(acc1,  1, 64);

        // ---- publish both columns: apply b_t, store {tag=t+1, value}
        if (lane == 0) {
            float w0 = acc0 * bring[(t & (RING - 1)) * COLS + c0];
            float w1 = acc1 * bring[(t & (RING - 1)) * COLS + c1];
            unsigned long long tg = ((unsigned long long)(t + 1)) << 32;
            __hip_atomic_store(&buf[(t & 1) * S + j0],
                               tg | (unsigned long long)__float_as_uint(w0),
                               __ATOMIC_RELAXED, __HIP_MEMORY_SCOPE_AGENT);
            __hip_atomic_store(&buf[(t & 1) * S + j0 + 1],
                               tg | (unsigned long long)__float_as_uint(w1),
                               __ATOMIC_RELAXED, __HIP_MEMORY_SCOPE_AGENT);
        }
    }

    // ---- final: block 0 sums alpha_{T-1} (tag == T) into out[0]
    if (g == 0) {
        unsigned long long want = (unsigned long long)T;
        unsigned long long* src = buf + (((T - 1) & 1) * S) + 4 * tid;
        unsigned long long v0, v1, v2, v3;
        for (;;) {
            v0 = __hip_atomic_load(&src[0], __ATOMIC_RELAXED, __HIP_MEMORY_SCOPE_AGENT);
            v1 = __hip_atomic_load(&src[1], __ATOMIC_RELAXED, __HIP_MEMORY_SCOPE_AGENT);
            v2 = __hip_atomic_load(&src[2], __ATOMIC_RELAXED, __HIP_MEMORY_SCOPE_AGENT);
            v3 = __hip_atomic_load(&src[3], __ATOMIC_RELAXED, __HIP_MEMORY_SCOPE_AGENT);
            if ((v0 >> 32) == want && (v1 >> 32) == want &&
                (v2 >> 32) == want && (v3 >> 32) == want) break;
            __builtin_amdgcn_s_sleep(1);
        }
        float sm = __uint_as_float((unsigned)v0) + __uint_as_float((unsigned)v1) +
                   __uint_as_float((unsigned)v2) + __uint_as_float((unsigned)v3);
        sm += __shfl_down(sm, 32, 64);
        sm += __shfl_down(sm, 16, 64);
        sm += __shfl_down(sm, 8, 64);
        sm += __shfl_down(sm, 4, 64);
        sm += __shfl_down(sm, 2, 64);
        sm += __shfl_down(sm, 1, 64);
        if (lane == 0) partial[wave] = sm;
        __syncthreads();
        if (tid == 0) {
            float tot = 0.f;
            for (int w = 0; w < 8; ++w) tot += partial[w];
            out[0] = tot;
        }
    }
}

extern "C" void kernel_launch(void* const* d_in, const int* in_sizes, int n_in,
                              void* d_out, int out_size, void* d_ws, size_t ws_size,
                              hipStream_t stream) {
    const int*   obs = (const int*)d_in[0];
    const float* A   = (const float*)d_in[1];
    const float* B   = (const float*)d_in[2];
    const float* pi  = (const float*)d_in[3];
    float* out = (float*)d_out;
    unsigned long long* buf = (unsigned long long*)d_ws;  // 2*S*8 = 32 KB

    // Allow >64KB dynamic LDS (idempotent host-side call; not a stream op).
    hipFuncSetAttribute((const void*)hmm_fwd,
                        hipFuncAttributeMaxDynamicSharedMemorySize, SMEM_BYTES);

    // No memset needed: 0xAA poison tag 0xAAAAAAAA never matches tags [1,4096].

    void* args[] = { (void*)&obs, (void*)&A, (void*)&B, (void*)&pi,
                     (void*)&out, (void*)&buf };
    hipLaunchCooperativeKernel((void*)hmm_fwd, dim3(G), dim3(BT), args,
                               SMEM_BYTES, stream);
}

// Round 5
// 9725.952 us; speedup vs baseline: 4.9998x; 2.7125x over previous
//
#include <hip/hip_runtime.h>

// HMM forward: alpha_t = (alpha_{t-1} @ A) * B[:, obs_t], out = sum(alpha_{T-1})
// S=2048, V=32768, T=4096. Persistent cooperative kernel.
//
// R4 = R0's comm skeleton (proven best: 128 blocks x 512 threads, 4 poll
// entries/thread, TWO barriers, single-wave coalesced 128B publish) with A
// staged once in 128KB dynamic LDS and per-step A fragments ds_read into
// PINNED registers BEFORE the poll loop (latency absorbed by the poll wait;
// LDS caps occupancy at 1 block/CU so VGPRs up to 256 are free).
//
// Evidence trail:
//  - R1/R3: per-wave scattered publish => 4x partial-line write-throughs
//    (WRITE_SIZE 262MB) serializing on the critical path. NEVER do that.
//  - R0: A reloaded from L2 each step (VGPR=56), mostly hidden under poll
//    but costs ~2048 distinct-line TCP requests/CU/step. LDS removes it.

#define S 2048
#define V 32768
#define T 4096
#define G 128          // blocks, cooperative, 1 per CU (LDS-capped)
#define BT 512         // 8 waves
#define COLS 16        // columns of A per block; thread c = tid&15
#define RING 16        // b-value ring slots
#define DIST 8         // b prefetch distance (steps)

// LDS floats: As 32768 | alpha 544 f4 | bring 256 | wpart 128 | fpart 8
#define SM_AS    0
#define SM_AL    32768
#define SM_BR    (32768 + 544 * 4)
#define SM_WP    (SM_BR + RING * COLS)
#define SM_FP    (SM_WP + 8 * COLS)
#define SMEM_FLOATS (SM_FP + 8)
#define SMEM_BYTES  (SMEM_FLOATS * 4)   // 141,856 B < 160 KiB

__global__ __launch_bounds__(BT, 1) void hmm_fwd(
    const int* __restrict__ obs,
    const float* __restrict__ A,
    const float* __restrict__ B,
    const float* __restrict__ pi,
    float* __restrict__ out,
    unsigned long long* __restrict__ buf)   // 2 * S pairs of {tag32, f32}
{
    extern __shared__ float smem[];
    float4* As4    = (float4*)(smem + SM_AS);  // As4[row4*16 + c]
    float4* al4    = (float4*)(smem + SM_AL);  // padded: idx p -> p + (p>>4)
    float*  bring  = smem + SM_BR;
    float*  wpart  = smem + SM_WP;
    float*  fpart  = smem + SM_FP;

    const int g    = blockIdx.x;
    const int tid  = threadIdx.x;
    const int lane = tid & 63;
    const int wave = tid >> 6;
    const int c    = tid & 15;            // column-within-block
    const int rg   = tid >> 4;            // row group 0..31 (rows rg*64..+63)
    const int j    = g * COLS + c;

    // ---- one-time: stage A slice into LDS.
    // Read: float4 across 4 consecutive columns of one row (coalesced).
    // Write: 4 scalar scatters into As4[row4*16 + col] layout.
    {
        const int u  = tid & 3;           // cols 4u..4u+3
        const int r0 = tid >> 2;          // rows, 128 per sweep
        for (int it = 0; it < 16; ++it) {
            int r = r0 + 128 * it;
            float4 av = *(const float4*)(A + (size_t)r * S + g * COLS + 4 * u);
            float* dst = smem + SM_AS + ((r >> 2) * 16) * 4 + (r & 3);
            dst[(4 * u + 0) * 4] = av.x;
            dst[(4 * u + 1) * 4] = av.y;
            dst[(4 * u + 2) * 4] = av.z;
            dst[(4 * u + 3) * 4] = av.w;
        }
    }

    // ---- wave 1: init b-ring (t=1..DIST). wave 0: publish alpha_0 (tag 1).
    if (wave == 1 && lane < COLS) {
        int jj = g * COLS + lane;
        for (int u = 1; u <= DIST; ++u) {
            int o = obs[u];
            bring[(u & (RING - 1)) * COLS + lane] = B[(size_t)jj * V + o];
        }
    }
    if (wave == 0 && lane < COLS) {
        int o0 = obs[0];
        float v = pi[j] * B[(size_t)j * V + o0];
        unsigned long long p = (1ull << 32) | (unsigned long long)__float_as_uint(v);
        __hip_atomic_store(&buf[j], p, __ATOMIC_RELAXED, __HIP_MEMORY_SCOPE_AGENT);
    }

    __syncthreads();   // A staged (and ring init ordered) before first use

    for (int t = 1; t < T; ++t) {
        // ---- A-fragment prefetch: rows rg*64..+63 of column c, from LDS,
        // issued BEFORE the poll so the poll wait absorbs the LDS latency.
        float4 af[16];
#pragma unroll
        for (int k = 0; k < 16; ++k) af[k] = As4[(rg * 16 + k) * 16 + c];
#pragma unroll
        for (int k = 0; k < 16; ++k)
            asm volatile("" : "+v"(af[k].x), "+v"(af[k].y),
                              "+v"(af[k].z), "+v"(af[k].w));

        // ---- poll alpha_{t-1} (tag == t); 4 entries per thread (32B)
        unsigned long long want = (unsigned long long)t;
        unsigned long long* src = buf + (((t - 1) & 1) * S) + 4 * tid;
        unsigned long long v0, v1, v2, v3;
        for (;;) {
            v0 = __hip_atomic_load(&src[0], __ATOMIC_RELAXED, __HIP_MEMORY_SCOPE_AGENT);
            v1 = __hip_atomic_load(&src[1], __ATOMIC_RELAXED, __HIP_MEMORY_SCOPE_AGENT);
            v2 = __hip_atomic_load(&src[2], __ATOMIC_RELAXED, __HIP_MEMORY_SCOPE_AGENT);
            v3 = __hip_atomic_load(&src[3], __ATOMIC_RELAXED, __HIP_MEMORY_SCOPE_AGENT);
            if ((v0 >> 32) == want && (v1 >> 32) == want &&
                (v2 >> 32) == want && (v3 >> 32) == want) break;
            __builtin_amdgcn_s_sleep(1);
        }
        float4 f;
        f.x = __uint_as_float((unsigned)v0);
        f.y = __uint_as_float((unsigned)v1);
        f.z = __uint_as_float((unsigned)v2);
        f.w = __uint_as_float((unsigned)v3);
        al4[tid + (tid >> 4)] = f;        // padded stage
        __syncthreads();   // B1: alpha staged

        // ---- b prefetch for t+DIST (wave 1, off critical path)
        if (wave == 1 && lane < COLS) {
            int tp = t + DIST;
            if (tp < T) {
                int o = obs[tp];
                bring[(tp & (RING - 1)) * COLS + lane] =
                    B[(size_t)(g * COLS + lane) * V + o];
            }
        }

        // ---- dot: 64 rows of column c; A already in regs, alpha from LDS
        float acc_a = 0.f, acc_b = 0.f;
#pragma unroll
        for (int k = 0; k < 16; ++k) {
            int p = rg * 16 + k;
            float4 al = al4[p + (p >> 4)];
            if (k & 1) {
                acc_b = fmaf(al.x, af[k].x, acc_b);
                acc_b = fmaf(al.y, af[k].y, acc_b);
                acc_b = fmaf(al.z, af[k].z, acc_b);
                acc_b = fmaf(al.w, af[k].w, acc_b);
            } else {
                acc_a = fmaf(al.x, af[k].x, acc_a);
                acc_a = fmaf(al.y, af[k].y, acc_a);
                acc_a = fmaf(al.z, af[k].z, acc_a);
                acc_a = fmaf(al.w, af[k].w, acc_a);
            }
        }
        float acc = acc_a + acc_b;
        // lanes {c, c+16, c+32, c+48} hold partials of column c
        acc += __shfl_down(acc, 32, 64);
        acc += __shfl_down(acc, 16, 64);
        if (lane < 16) wpart[wave * 16 + lane] = acc;
        __syncthreads();   // B2: partials ready

        // ---- epilogue: wave 0 sums, applies b_t, ONE coalesced 128B publish
        if (wave == 0 && lane < 16) {
            float s = 0.f;
#pragma unroll
            for (int w = 0; w < 8; ++w) s += wpart[w * 16 + lane];
            float val = s * bring[(t & (RING - 1)) * COLS + lane];
            unsigned long long p = (((unsigned long long)(t + 1)) << 32) |
                                   (unsigned long long)__float_as_uint(val);
            __hip_atomic_store(&buf[(t & 1) * S + g * COLS + lane], p,
                               __ATOMIC_RELAXED, __HIP_MEMORY_SCOPE_AGENT);
        }
    }

    // ---- final: block 0 sums alpha_{T-1} (tag == T) into out[0]
    if (g == 0) {
        unsigned long long want = (unsigned long long)T;
        unsigned long long* src = buf + (((T - 1) & 1) * S) + 4 * tid;
        unsigned long long v0, v1, v2, v3;
        for (;;) {
            v0 = __hip_atomic_load(&src[0], __ATOMIC_RELAXED, __HIP_MEMORY_SCOPE_AGENT);
            v1 = __hip_atomic_load(&src[1], __ATOMIC_RELAXED, __HIP_MEMORY_SCOPE_AGENT);
            v2 = __hip_atomic_load(&src[2], __ATOMIC_RELAXED, __HIP_MEMORY_SCOPE_AGENT);
            v3 = __hip_atomic_load(&src[3], __ATOMIC_RELAXED, __HIP_MEMORY_SCOPE_AGENT);
            if ((v0 >> 32) == want && (v1 >> 32) == want &&
                (v2 >> 32) == want && (v3 >> 32) == want) break;
            __builtin_amdgcn_s_sleep(1);
        }
        float sm = __uint_as_float((unsigned)v0) + __uint_as_float((unsigned)v1) +
                   __uint_as_float((unsigned)v2) + __uint_as_float((unsigned)v3);
        sm += __shfl_down(sm, 32, 64);
        sm += __shfl_down(sm, 16, 64);
        sm += __shfl_down(sm, 8, 64);
        sm += __shfl_down(sm, 4, 64);
        sm += __shfl_down(sm, 2, 64);
        sm += __shfl_down(sm, 1, 64);
        if (lane == 0) fpart[wave] = sm;
        __syncthreads();
        if (tid == 0) {
            float tot = 0.f;
            for (int w = 0; w < 8; ++w) tot += fpart[w];
            out[0] = tot;
        }
    }
}

extern "C" void kernel_launch(void* const* d_in, const int* in_sizes, int n_in,
                              void* d_out, int out_size, void* d_ws, size_t ws_size,
                              hipStream_t stream) {
    const int*   obs = (const int*)d_in[0];
    const float* A   = (const float*)d_in[1];
    const float* B   = (const float*)d_in[2];
    const float* pi  = (const float*)d_in[3];
    float* out = (float*)d_out;
    unsigned long long* buf = (unsigned long long*)d_ws;  // 2*S*8 = 32 KB

    hipFuncSetAttribute((const void*)hmm_fwd,
                        hipFuncAttributeMaxDynamicSharedMemorySize, SMEM_BYTES);

    // No memset needed: 0xAA poison tag 0xAAAAAAAA never matches tags [1,4096].

    void* args[] = { (void*)&obs, (void*)&A, (void*)&B, (void*)&pi,
                     (void*)&out, (void*)&buf };
    hipLaunchCooperativeKernel((void*)hmm_fwd, dim3(G), dim3(BT), args,
                               SMEM_BYTES, stream);
}